// Round 2
// baseline (955.863 us; speedup 1.0000x reference)
//
#include <hip/hip_runtime.h>
#include <math.h>

#define F_IN 512
#define HID  16
#define NCLS 40

typedef __attribute__((ext_vector_type(8))) short short8;
typedef __attribute__((ext_vector_type(4))) float floatx4;

// ---------- bf16 helpers ----------
__device__ __forceinline__ unsigned short bf16_rne(float f) {
    unsigned u = __float_as_uint(f);
    u += 0x7fffu + ((u >> 16) & 1u);
    return (unsigned short)(u >> 16);
}
__device__ __forceinline__ float bf16_f32(unsigned short s) {
    return __uint_as_float(((unsigned)s) << 16);
}

// ---------- init: deg = 1 (self loop), cnt = 0 ----------
__global__ void k_init(float* __restrict__ deg, int* __restrict__ cnt, int n) {
    int i = blockIdx.x * 256 + threadIdx.x;
    if (i < n) { deg[i] = 1.0f; cnt[i] = 0; }
}

// ---------- edge pass 1: weighted degree + count per destination ----------
__global__ void k_edge1(const int* __restrict__ col, const float* __restrict__ w,
                        float* __restrict__ deg, int* __restrict__ cnt, int E) {
    int i = blockIdx.x * 256 + threadIdx.x;
    if (i < E) {
        int c = col[i];
        atomicAdd(&deg[c], w[i]);
        atomicAdd(&cnt[c], 1);
    }
}

__global__ void k_dis(const float* __restrict__ deg, float* __restrict__ dis, int n) {
    int i = blockIdx.x * 256 + threadIdx.x;
    if (i < n) dis[i] = rsqrtf(deg[i]);
}

// ---------- exclusive scan of cnt -> rowptr (3 kernels) ----------
__global__ void k_scan_local(const int* __restrict__ cnt, int* __restrict__ rowptr,
                             int* __restrict__ bsum, int N) {
    __shared__ int s[256];
    int t = threadIdx.x;
    int i = blockIdx.x * 256 + t;
    int v = (i < N) ? cnt[i] : 0;
    s[t] = v; __syncthreads();
    for (int off = 1; off < 256; off <<= 1) {
        int a = (t >= off) ? s[t - off] : 0;
        __syncthreads();
        s[t] += a;
        __syncthreads();
    }
    if (i < N) rowptr[i] = s[t] - v;       // local exclusive
    if (t == 255) bsum[blockIdx.x] = s[255];
}

__global__ void k_scan_bsum(int* __restrict__ bsum, int nb) {
    __shared__ int s[512];
    int t = threadIdx.x;
    int v = (t < nb) ? bsum[t] : 0;
    s[t] = v; __syncthreads();
    for (int off = 1; off < 512; off <<= 1) {
        int a = (t >= off) ? s[t - off] : 0;
        __syncthreads();
        s[t] += a;
        __syncthreads();
    }
    if (t < nb) bsum[t] = s[t] - v;        // exclusive
}

__global__ void k_scan_add(int* __restrict__ rowptr, int* __restrict__ cursor,
                           const int* __restrict__ bsum, int N, int E) {
    int i = blockIdx.x * 256 + threadIdx.x;
    if (i < N) {
        int v = rowptr[i] + bsum[blockIdx.x];
        rowptr[i] = v;
        cursor[i] = v;
    }
    if (i == 0) rowptr[N] = E;
}

// ---------- edge pass 2: scatter edges into CSR-by-destination ----------
__global__ void k_permute(const int* __restrict__ row, const int* __restrict__ col,
                          const float* __restrict__ w, const float* __restrict__ dis,
                          int* __restrict__ cursor, float2* __restrict__ sedge, int E) {
    int i = blockIdx.x * 256 + threadIdx.x;
    if (i < E) {
        int r = row[i], c = col[i];
        float nrm = dis[r] * w[i] * dis[c];
        int pos = atomicAdd(&cursor[c], 1);
        sedge[pos] = make_float2(__int_as_float(r), nrm);
    }
}

// ---------- h1 = x @ W1 via 16x16x32 bf16 MFMA, hi/lo split ----------
// block = 256 (4 waves); wave w handles tile blockIdx.x*4+w (16 nodes).
// W1 staged in LDS as bf16 hi/lo, transposed [h][k] with +8 pad.
__global__ void k_xw1_mfma(const float* __restrict__ x, const float* __restrict__ W1,
                           float* __restrict__ h1, int N, int nTiles) {
    __shared__ unsigned short wh[HID][F_IN + 8];
    __shared__ unsigned short wl[HID][F_IN + 8];
    for (int f = threadIdx.x; f < F_IN * HID; f += 256) {
        int k = f >> 4, h = f & 15;
        float v = W1[f];
        unsigned short hhi = bf16_rne(v);
        float rem = v - bf16_f32(hhi);
        wh[h][k] = hhi;
        wl[h][k] = (unsigned short)(__float_as_uint(rem) >> 16);
    }
    __syncthreads();

    int wave = threadIdx.x >> 6;
    int lane = threadIdx.x & 63;
    int tile = blockIdx.x * 4 + wave;
    if (tile >= nTiles) return;

    int m    = lane & 15;          // node within tile (A row)
    int quad = lane >> 4;          // k-block selector
    int node = tile * 16 + m;
    if (node >= N) node = N - 1;   // clamp; row m output not stored anyway
    const float* xr = x + (size_t)node * F_IN;

    floatx4 acc = {0.f, 0.f, 0.f, 0.f};

    #pragma unroll 4
    for (int s = 0; s < F_IN / 32; ++s) {
        int k0 = s * 32 + quad * 8;
        float4 v0 = *(const float4*)(xr + k0);
        float4 v1 = *(const float4*)(xr + k0 + 4);
        float xv[8] = {v0.x, v0.y, v0.z, v0.w, v1.x, v1.y, v1.z, v1.w};
        short8 ah, al;
        #pragma unroll
        for (int j = 0; j < 8; ++j) {
            unsigned short hhi = bf16_rne(xv[j]);
            float rem = xv[j] - bf16_f32(hhi);
            ah[j] = (short)hhi;
            al[j] = (short)(unsigned short)(__float_as_uint(rem) >> 16);
        }
        short8 bh = *(const short8*)&wh[m][k0];   // B frag: n = lane&15 -> channel
        short8 bl = *(const short8*)&wl[m][k0];
        acc = __builtin_amdgcn_mfma_f32_16x16x32_bf16(ah, bh, acc, 0, 0, 0);
        acc = __builtin_amdgcn_mfma_f32_16x16x32_bf16(ah, bl, acc, 0, 0, 0);
        acc = __builtin_amdgcn_mfma_f32_16x16x32_bf16(al, bh, acc, 0, 0, 0);
    }

    // C/D: col = lane&15 (channel), row = quad*4 + reg (node in tile)
    int h = lane & 15;
    #pragma unroll
    for (int r = 0; r < 4; ++r) {
        int nrow = tile * 16 + quad * 4 + r;
        if (nrow < N) h1[(size_t)nrow * HID + h] = acc[r];
    }
}

// ---------- atomic-free aggregation: dst[n] = sum_e norm*src[row_e] + selfloop ----------
__global__ void k_gather(const float2* __restrict__ sedge, const int* __restrict__ rowptr,
                         const float* __restrict__ dis, const float* __restrict__ src,
                         const float* __restrict__ bias, float* __restrict__ dst,
                         int N, int do_relu) {
    int i = blockIdx.x * 256 + threadIdx.x;
    int node = i >> 4, h = i & 15;
    if (node >= N) return;
    float d = dis[node];
    float acc = src[(size_t)node * HID + h] * d * d;   // self loop: dis*1*dis
    int s = rowptr[node], e = rowptr[node + 1];
    for (int j = s; j < e; ++j) {
        float2 p = sedge[j];
        int r = __float_as_int(p.x);
        acc = fmaf(p.y, src[(size_t)r * HID + h], acc);
    }
    if (bias) acc += bias[h];
    if (do_relu) acc = acc > 0.f ? acc : 0.f;
    dst[i] = acc;
}

// ---------- out = log_softmax(agg2 @ W2 + b2) ----------
__global__ void k_final(const float* __restrict__ B, const float* __restrict__ W2,
                        const float* __restrict__ b2, float* __restrict__ out, int N) {
    __shared__ float w2s[HID * NCLS];
    __shared__ float b2s[NCLS];
    for (int f = threadIdx.x; f < HID * NCLS; f += 256) w2s[f] = W2[f];
    if (threadIdx.x < NCLS) b2s[threadIdx.x] = b2[threadIdx.x];
    __syncthreads();
    int nd = blockIdx.x * 256 + threadIdx.x;
    if (nd < N) {
        float a[HID];
        const float4* ap = (const float4*)(B + (size_t)nd * HID);
        #pragma unroll
        for (int q = 0; q < 4; ++q) {
            float4 v = ap[q];
            a[q * 4 + 0] = v.x; a[q * 4 + 1] = v.y;
            a[q * 4 + 2] = v.z; a[q * 4 + 3] = v.w;
        }
        float y[NCLS];
        #pragma unroll
        for (int c = 0; c < NCLS; ++c) y[c] = b2s[c];
        #pragma unroll
        for (int hh = 0; hh < HID; ++hh) {
            float av = a[hh];
            #pragma unroll
            for (int c = 0; c < NCLS; ++c) y[c] = fmaf(av, w2s[hh * NCLS + c], y[c]);
        }
        float m = y[0];
        #pragma unroll
        for (int c = 1; c < NCLS; ++c) m = fmaxf(m, y[c]);
        float sum = 0.f;
        #pragma unroll
        for (int c = 0; c < NCLS; ++c) sum += expf(y[c] - m);
        float base = m + logf(sum);
        float* op = out + (size_t)nd * NCLS;
        #pragma unroll
        for (int c = 0; c < NCLS; ++c) op[c] = y[c] - base;
    }
}

// ---------- launch ----------
extern "C" void kernel_launch(void* const* d_in, const int* in_sizes, int n_in,
                              void* d_out, int out_size, void* d_ws, size_t ws_size,
                              hipStream_t stream) {
    const float* x  = (const float*)d_in[0];
    const int*   ei = (const int*)d_in[1];
    const float* ew = (const float*)d_in[2];
    const float* W1 = (const float*)d_in[3];
    const float* b1 = (const float*)d_in[4];
    const float* W2 = (const float*)d_in[5];
    const float* b2 = (const float*)d_in[6];
    float* out = (float*)d_out;

    int N = in_sizes[0] / F_IN;      // 100000
    int E = in_sizes[2];             // 3200000
    const int* row = ei;
    const int* col = ei + E;

    // workspace layout (16B-aligned chunks first)
    char* w = (char*)d_ws;
    float2* sedge = (float2*)w;                      size_t off = (size_t)E * 8;
    float*  A     = (float*)(w + off);               off += (size_t)N * HID * 4;  // h1 / agg2
    float*  Bb    = (float*)(w + off);               off += (size_t)N * HID * 4;  // z1
    float*  deg   = (float*)(w + off);               off += (size_t)N * 4;
    float*  dis   = (float*)(w + off);               off += (size_t)N * 4;
    int*    cnt   = (int*)(w + off);                 off += (size_t)N * 4;
    int*    cursor= (int*)(w + off);                 off += (size_t)N * 4;
    int*    rowptr= (int*)(w + off);                 off += (size_t)(N + 1) * 4;
    int*    bsum  = (int*)(w + off);                 off += 512 * 4;

    dim3 blk(256);
    int gN  = (N + 255) / 256;
    int gE  = (E + 255) / 256;
    int n16 = N * HID;
    int g16 = (n16 + 255) / 256;

    // norm + CSR build
    k_init<<<dim3(gN), blk, 0, stream>>>(deg, cnt, N);
    k_edge1<<<dim3(gE), blk, 0, stream>>>(col, ew, deg, cnt, E);
    k_dis<<<dim3(gN), blk, 0, stream>>>(deg, dis, N);
    k_scan_local<<<dim3(gN), blk, 0, stream>>>(cnt, rowptr, bsum, N);
    k_scan_bsum<<<dim3(1), dim3(512), 0, stream>>>(bsum, gN);
    k_scan_add<<<dim3(gN), blk, 0, stream>>>(rowptr, cursor, bsum, N, E);
    k_permute<<<dim3(gE), blk, 0, stream>>>(row, col, ew, dis, cursor, sedge, E);

    // h1 = x @ W1 (MFMA)
    int nTiles = (N + 15) / 16;
    int gT = (nTiles + 3) / 4;
    k_xw1_mfma<<<dim3(gT), blk, 0, stream>>>(x, W1, A, N, nTiles);

    // z1 = relu(Ahat*h1 + b1) ; agg2 = Ahat*z1
    k_gather<<<dim3(g16), blk, 0, stream>>>(sedge, rowptr, dis, A, b1, Bb, N, 1);
    k_gather<<<dim3(g16), blk, 0, stream>>>(sedge, rowptr, dis, Bb, (const float*)nullptr, A, N, 0);

    // out
    k_final<<<dim3(gN), blk, 0, stream>>>(A, W2, b2, out, N);
}